// Round 1
// baseline (486.768 us; speedup 1.0000x reference)
//
#include <hip/hip_runtime.h>

typedef _Float16 half8 __attribute__((ext_vector_type(8)));
typedef _Float16 half4 __attribute__((ext_vector_type(4)));
typedef float floatx4 __attribute__((ext_vector_type(4)));

#define ASYNC16(g, l) __builtin_amdgcn_global_load_lds( \
    (const __attribute__((address_space(1))) void*)(g),  \
    (__attribute__((address_space(3))) void*)(l), 16, 0, 0)

// ---------------------------------------------------------------------------
// fp32 -> fp16 bulk convert (vectorized, grid-stride)
// ---------------------------------------------------------------------------
__global__ void cvt_f2h(const float* __restrict__ in, _Float16* __restrict__ out, int n4)
{
    int i = blockIdx.x * blockDim.x + threadIdx.x;
    const int stride = gridDim.x * blockDim.x;
    for (; i < n4; i += stride) {
        float4 v = ((const float4*)in)[i];
        half4 h = { (_Float16)v.x, (_Float16)v.y, (_Float16)v.z, (_Float16)v.w };
        ((half4*)out)[i] = h;
    }
}

// ---------------------------------------------------------------------------
// W [K=1024][N=1024] fp32  ->  Wt [N][K] fp16   (z = which of Wq/Wk/Wv)
// ---------------------------------------------------------------------------
__global__ void transpose_w(const float* __restrict__ Wq, const float* __restrict__ Wk,
                            const float* __restrict__ Wv, _Float16* __restrict__ Wt)
{
    const float* W = (blockIdx.z == 0) ? Wq : (blockIdx.z == 1) ? Wk : Wv;
    _Float16* out = Wt + (size_t)blockIdx.z * 1024 * 1024;
    __shared__ float t[32][33];
    const int tx = threadIdx.x, ty = threadIdx.y;     // (32,8)
    const int k0 = blockIdx.x * 32, n0 = blockIdx.y * 32;
#pragma unroll
    for (int i = 0; i < 32; i += 8)
        t[ty + i][tx] = W[(size_t)(k0 + ty + i) * 1024 + n0 + tx];   // t[k][n]
    __syncthreads();
#pragma unroll
    for (int i = 0; i < 32; i += 8)
        out[(size_t)(n0 + ty + i) * 1024 + k0 + tx] = (_Float16)t[tx][ty + i];  // out[n][k]=W[k][n]
}

// ---------------------------------------------------------------------------
// QKV GEMM: C[16384 x 3072] = xh[16384x1024] @ [Wq|Wk|Wv] + bias
//   Wt is [3072][1024] (transposed), 128x128 tile, BK=32, 4 waves (2x2 of 64x64)
//   epilogue: Q,K row-major fp16; V transposed per batch (Vt[b][d][s]) fp16
// ---------------------------------------------------------------------------
__global__ __launch_bounds__(256, 2)
void gemm_qkv(const _Float16* __restrict__ X, const _Float16* __restrict__ Wt,
              const float* __restrict__ bq, const float* __restrict__ bk,
              const float* __restrict__ bv,
              _Float16* __restrict__ Qh, _Float16* __restrict__ Kh, _Float16* __restrict__ Vt)
{
    __shared__ __align__(16) _Float16 sA[128 * 32];
    __shared__ __align__(16) _Float16 sB[128 * 32];
    const int tid = threadIdx.x;
    const int lane = tid & 63, wave = tid >> 6;
    const int quad = lane >> 4, l15 = lane & 15;
    const int wm = (wave & 1) * 64, wn = (wave >> 1) * 64;
    const long m0 = (long)blockIdx.y * 128;
    const int  n0 = blockIdx.x * 128;

    const _Float16* Ab = X + m0 * 1024;
    const _Float16* Bb = Wt + (long)n0 * 1024;

    const int c0 = tid, c1 = tid + 256;
    const long offA0 = (long)(c0 >> 2) * 1024 + (c0 & 3) * 8;
    const long offA1 = (long)(c1 >> 2) * 1024 + (c1 & 3) * 8;

    floatx4 acc[4][4] = {};

    for (int k0 = 0; k0 < 1024; k0 += 32) {
        __syncthreads();
        ASYNC16(Ab + offA0 + k0, (char*)sA + c0 * 16);
        ASYNC16(Ab + offA1 + k0, (char*)sA + c1 * 16);
        ASYNC16(Bb + offA0 + k0, (char*)sB + c0 * 16);
        ASYNC16(Bb + offA1 + k0, (char*)sB + c1 * 16);
        __syncthreads();
        half8 af[4], bf[4];
#pragma unroll
        for (int i = 0; i < 4; ++i) {
            af[i] = *(const half8*)(sA + (wm + i * 16 + l15) * 32 + quad * 8);
            bf[i] = *(const half8*)(sB + (wn + i * 16 + l15) * 32 + quad * 8);
        }
#pragma unroll
        for (int i = 0; i < 4; ++i)
#pragma unroll
            for (int j = 0; j < 4; ++j)
                acc[i][j] = __builtin_amdgcn_mfma_f32_16x16x32_f16(af[i], bf[j], acc[i][j], 0, 0, 0);
    }

    const int which = n0 >> 10;           // 0=Q 1=K 2=V
    const int ncol0 = n0 & 1023;
    const float* bias = (which == 0) ? bq : (which == 1) ? bk : bv;

    if (which < 2) {
        _Float16* O = which ? Kh : Qh;
#pragma unroll
        for (int i = 0; i < 4; ++i) {
            const long mb = m0 + wm + i * 16 + quad * 4;
#pragma unroll
            for (int j = 0; j < 4; ++j) {
                const int col = ncol0 + wn + j * 16 + l15;
                const float bb = bias[col];
                _Float16* op = O + mb * 1024 + col;
#pragma unroll
                for (int r = 0; r < 4; ++r)
                    op[(long)r * 1024] = (_Float16)(acc[i][j][r] + bb);
            }
        }
    } else {
#pragma unroll
        for (int i = 0; i < 4; ++i) {
            const long mb = m0 + wm + i * 16 + quad * 4;
            const int b = (int)(mb >> 11);
            const int s = (int)(mb & 2047);
#pragma unroll
            for (int j = 0; j < 4; ++j) {
                const int col = ncol0 + wn + j * 16 + l15;
                const float bb = bias[col];
                half4 h;
#pragma unroll
                for (int r = 0; r < 4; ++r) h[r] = (_Float16)(acc[i][j][r] + bb);
                *(half4*)(Vt + (long)b * 2097152 + (long)col * 2048 + s) = h;  // 4 consecutive seq
            }
        }
    }
}

// ---------------------------------------------------------------------------
// Generic bt-form GEMM: C[m][n] = sum_k A[m][k]*B[n][k], fp16 in, fp32 out
//   grid (ntile, mtile, z);  z adds per-operand strides (batching)
// ---------------------------------------------------------------------------
__global__ __launch_bounds__(256, 2)
void gemm_bt(const _Float16* __restrict__ A, long sAz, int lda,
             const _Float16* __restrict__ B, long sBz, int ldb,
             float* __restrict__ C, long sCz, int ldc, int K)
{
    __shared__ __align__(16) _Float16 sA[128 * 32];
    __shared__ __align__(16) _Float16 sB[128 * 32];
    const int tid = threadIdx.x;
    const int lane = tid & 63, wave = tid >> 6;
    const int quad = lane >> 4, l15 = lane & 15;
    const int wm = (wave & 1) * 64, wn = (wave >> 1) * 64;
    const long m0 = (long)blockIdx.y * 128;
    const long n0 = (long)blockIdx.x * 128;

    const _Float16* Ab = A + (long)blockIdx.z * sAz + m0 * lda;
    const _Float16* Bb = B + (long)blockIdx.z * sBz + n0 * ldb;
    float* Cb = C + (long)blockIdx.z * sCz;

    const int c0 = tid, c1 = tid + 256;
    const long offA0 = (long)(c0 >> 2) * lda + (c0 & 3) * 8;
    const long offA1 = (long)(c1 >> 2) * lda + (c1 & 3) * 8;
    const long offB0 = (long)(c0 >> 2) * ldb + (c0 & 3) * 8;
    const long offB1 = (long)(c1 >> 2) * ldb + (c1 & 3) * 8;

    floatx4 acc[4][4] = {};

    for (int k0 = 0; k0 < K; k0 += 32) {
        __syncthreads();
        ASYNC16(Ab + offA0 + k0, (char*)sA + c0 * 16);
        ASYNC16(Ab + offA1 + k0, (char*)sA + c1 * 16);
        ASYNC16(Bb + offB0 + k0, (char*)sB + c0 * 16);
        ASYNC16(Bb + offB1 + k0, (char*)sB + c1 * 16);
        __syncthreads();
        half8 af[4], bf[4];
#pragma unroll
        for (int i = 0; i < 4; ++i) {
            af[i] = *(const half8*)(sA + (wm + i * 16 + l15) * 32 + quad * 8);
            bf[i] = *(const half8*)(sB + (wn + i * 16 + l15) * 32 + quad * 8);
        }
#pragma unroll
        for (int i = 0; i < 4; ++i)
#pragma unroll
            for (int j = 0; j < 4; ++j)
                acc[i][j] = __builtin_amdgcn_mfma_f32_16x16x32_f16(af[i], bf[j], acc[i][j], 0, 0, 0);
    }

#pragma unroll
    for (int i = 0; i < 4; ++i) {
        const long mb = m0 + wm + i * 16 + quad * 4;
#pragma unroll
        for (int j = 0; j < 4; ++j) {
            const long n = n0 + wn + j * 16 + l15;
            float* cp = Cb + mb * ldc + n;
#pragma unroll
            for (int r = 0; r < 4; ++r)
                cp[(long)r * ldc] = acc[i][j][r];
        }
    }
}

// ---------------------------------------------------------------------------
// Row softmax over 2048 fp32 scores; writes fp16 weights IN PLACE at the row
// start (context GEMM then uses lda = 4096 halfs). One block per row.
// ---------------------------------------------------------------------------
__global__ __launch_bounds__(256)
void softmax_rows(float* __restrict__ scores)
{
    float* row = scores + ((size_t)blockIdx.y * 2048 + blockIdx.x) * 2048;
    const int tid = threadIdx.x;
    const int wave = tid >> 6;
    float4 v0 = ((const float4*)row)[tid];        // elems 4t..4t+3
    float4 v1 = ((const float4*)row)[tid + 256];  // elems 1024+4t..
    __shared__ float red[8];

    float m = fmaxf(fmaxf(fmaxf(v0.x, v0.y), fmaxf(v0.z, v0.w)),
                    fmaxf(fmaxf(v1.x, v1.y), fmaxf(v1.z, v1.w)));
#pragma unroll
    for (int off = 32; off > 0; off >>= 1) m = fmaxf(m, __shfl_xor(m, off));
    if ((tid & 63) == 0) red[wave] = m;
    __syncthreads();
    m = fmaxf(fmaxf(red[0], red[1]), fmaxf(red[2], red[3]));

    float e[8];
    e[0] = __expf(v0.x - m); e[1] = __expf(v0.y - m);
    e[2] = __expf(v0.z - m); e[3] = __expf(v0.w - m);
    e[4] = __expf(v1.x - m); e[5] = __expf(v1.y - m);
    e[6] = __expf(v1.z - m); e[7] = __expf(v1.w - m);
    float s = ((e[0] + e[1]) + (e[2] + e[3])) + ((e[4] + e[5]) + (e[6] + e[7]));
#pragma unroll
    for (int off = 32; off > 0; off >>= 1) s += __shfl_xor(s, off);
    if ((tid & 63) == 0) red[4 + wave] = s;
    __syncthreads();
    s = (red[4] + red[5]) + (red[6] + red[7]);
    const float inv = 1.0f / s;

    _Float16* wrow = (_Float16*)row;
    half4 h0, h1;
#pragma unroll
    for (int r = 0; r < 4; ++r) h0[r] = (_Float16)(e[r] * inv);
#pragma unroll
    for (int r = 0; r < 4; ++r) h1[r] = (_Float16)(e[4 + r] * inv);
    ((half4*)wrow)[tid] = h0;
    ((half4*)wrow)[tid + 256] = h1;
}

// ---------------------------------------------------------------------------
extern "C" void kernel_launch(void* const* d_in, const int* in_sizes, int n_in,
                              void* d_out, int out_size, void* d_ws, size_t ws_size,
                              hipStream_t stream)
{
    const float* x  = (const float*)d_in[0];
    const float* Wq = (const float*)d_in[1];
    const float* bq = (const float*)d_in[2];
    const float* Wk = (const float*)d_in[3];
    const float* bk = (const float*)d_in[4];
    const float* Wv = (const float*)d_in[5];
    const float* bv = (const float*)d_in[6];
    float* out = (float*)d_out;

    char* ws = (char*)d_ws;
    _Float16* Qh = (_Float16*)ws;          // [16384][1024] fp16
    _Float16* Kh = Qh + 16777216;          // [16384][1024] fp16
    _Float16* Vt = Kh + 16777216;          // 8 x [1024][2048] fp16 (V transposed per batch)
    char* region = ws + 100663296;         // shared region: (xh+Wt) then scores
    _Float16* xh = (_Float16*)region;      // [16384][1024] fp16   (dead after QKV GEMM)
    _Float16* Wt = xh + 16777216;          // [3072][1024] fp16    (dead after QKV GEMM)
    float* scores = (float*)region;        // c x [2048][2048] fp32 (overwrites xh/Wt)

    // pick batch-chunk c so that 100663296 + max(39845888, c*16MiB*... ) fits ws
    int c = 8;
    for (;;) {
        size_t region_sz = (size_t)c * 16777216ull;       // c * 2048*2048*4 B
        if (region_sz < 39845888ull) region_sz = 39845888ull;
        if (100663296ull + region_sz <= ws_size || c == 1) break;
        c >>= 1;
    }

    cvt_f2h<<<2048, 256, 0, stream>>>(x, xh, 16777216 / 4);
    transpose_w<<<dim3(32, 32, 3), dim3(32, 8, 1), 0, stream>>>(Wq, Wk, Wv, Wt);
    gemm_qkv<<<dim3(24, 128, 1), 256, 0, stream>>>(xh, Wt, bq, bk, bv, Qh, Kh, Vt);

    for (int b0 = 0; b0 < 8; b0 += c) {
        int cc = (8 - b0 < c) ? (8 - b0) : c;
        // scores[z] = Q_b @ K_b^T   (M=N=2048, K=1024)
        gemm_bt<<<dim3(16, 16, cc), 256, 0, stream>>>(
            Qh + (long)b0 * 2097152, 2097152L, 1024,
            Kh + (long)b0 * 2097152, 2097152L, 1024,
            scores, 4194304L, 2048, 1024);
        // softmax per row, fp16 weights written in place (row stride 4096 halfs)
        softmax_rows<<<dim3(2048, cc, 1), 256, 0, stream>>>(scores);
        // context[z] = P @ V  via bt-form with Vt[n=d][k=seq]  (M=2048,N=1024,K=2048)
        gemm_bt<<<dim3(8, 16, cc), 256, 0, stream>>>(
            (const _Float16*)scores, 8388608L, 4096,
            Vt + (long)b0 * 2097152, 2097152L, 2048,
            out + (long)b0 * 2097152, 2097152L, 1024, 2048);
    }
}

// Round 2
// 473.123 us; speedup vs baseline: 1.0288x; 1.0288x over previous
//
#include <hip/hip_runtime.h>

typedef _Float16 half8 __attribute__((ext_vector_type(8)));
typedef _Float16 half4 __attribute__((ext_vector_type(4)));
typedef float floatx4 __attribute__((ext_vector_type(4)));

#define ASYNC16(g, l) __builtin_amdgcn_global_load_lds( \
    (const __attribute__((address_space(1))) void*)(g),  \
    (__attribute__((address_space(3))) void*)(l), 16, 0, 0)

// ---------------------------------------------------------------------------
// fp32 -> fp16 bulk convert (vectorized, grid-stride)
// ---------------------------------------------------------------------------
__global__ void cvt_f2h(const float* __restrict__ in, _Float16* __restrict__ out, int n4)
{
    int i = blockIdx.x * blockDim.x + threadIdx.x;
    const int stride = gridDim.x * blockDim.x;
    for (; i < n4; i += stride) {
        float4 v = ((const float4*)in)[i];
        half4 h = { (_Float16)v.x, (_Float16)v.y, (_Float16)v.z, (_Float16)v.w };
        ((half4*)out)[i] = h;
    }
}

// ---------------------------------------------------------------------------
// W [K=1024][N=1024] fp32  ->  Wt [N][K] fp16   (z = which of Wq/Wk/Wv)
// ---------------------------------------------------------------------------
__global__ void transpose_w(const float* __restrict__ Wq, const float* __restrict__ Wk,
                            const float* __restrict__ Wv, _Float16* __restrict__ Wt)
{
    const float* W = (blockIdx.z == 0) ? Wq : (blockIdx.z == 1) ? Wk : Wv;
    _Float16* out = Wt + (size_t)blockIdx.z * 1024 * 1024;
    __shared__ float t[32][33];
    const int tx = threadIdx.x, ty = threadIdx.y;     // (32,8)
    const int k0 = blockIdx.x * 32, n0 = blockIdx.y * 32;
#pragma unroll
    for (int i = 0; i < 32; i += 8)
        t[ty + i][tx] = W[(size_t)(k0 + ty + i) * 1024 + n0 + tx];   // t[k][n]
    __syncthreads();
#pragma unroll
    for (int i = 0; i < 32; i += 8)
        out[(size_t)(n0 + ty + i) * 1024 + k0 + tx] = (_Float16)t[tx][ty + i];  // out[n][k]=W[k][n]
}

// ---------------------------------------------------------------------------
// QKV GEMM: C[16384 x 3072] = xh[16384x1024] @ [Wq|Wk|Wv] + bias
//   Wt is [3072][1024] (transposed), 128x128 tile, BK=64, 4 waves (2x2 of 64x64)
//   epilogue: Q,K row-major fp16; V transposed per batch (Vt[b][d][s]) fp16
// ---------------------------------------------------------------------------
__global__ __launch_bounds__(256, 2)
void gemm_qkv(const _Float16* __restrict__ X, const _Float16* __restrict__ Wt,
              const float* __restrict__ bq, const float* __restrict__ bk,
              const float* __restrict__ bv,
              _Float16* __restrict__ Qh, _Float16* __restrict__ Kh, _Float16* __restrict__ Vt)
{
    __shared__ __align__(16) _Float16 sA[128 * 64];
    __shared__ __align__(16) _Float16 sB[128 * 64];
    const int tid = threadIdx.x;
    const int lane = tid & 63, wave = tid >> 6;
    const int quad = lane >> 4, l15 = lane & 15;
    const int wm = (wave & 1) * 64, wn = (wave >> 1) * 64;
    const long m0 = (long)blockIdx.y * 128;
    const int  n0 = blockIdx.x * 128;

    const _Float16* Ab = X + m0 * 1024;
    const _Float16* Bb = Wt + (long)n0 * 1024;

    // BK=64: 128 rows x 8 chunks(16B) = 1024 chunks per operand, 4 per thread
    long offA[4];
    int ldsOff[4];
#pragma unroll
    for (int u = 0; u < 4; ++u) {
        const int c = tid + u * 256;
        offA[u] = (long)(c >> 3) * 1024 + (c & 7) * 8;
        ldsOff[u] = c * 16;
    }

    floatx4 acc[4][4] = {};

    for (int k0 = 0; k0 < 1024; k0 += 64) {
        __syncthreads();
#pragma unroll
        for (int u = 0; u < 4; ++u) {
            ASYNC16(Ab + offA[u] + k0, (char*)sA + ldsOff[u]);
            ASYNC16(Bb + offA[u] + k0, (char*)sB + ldsOff[u]);
        }
        __syncthreads();
#pragma unroll
        for (int s = 0; s < 2; ++s) {
            half8 af[4], bf[4];
#pragma unroll
            for (int i = 0; i < 4; ++i) {
                af[i] = *(const half8*)(sA + (wm + i * 16 + l15) * 64 + s * 32 + quad * 8);
                bf[i] = *(const half8*)(sB + (wn + i * 16 + l15) * 64 + s * 32 + quad * 8);
            }
#pragma unroll
            for (int i = 0; i < 4; ++i)
#pragma unroll
                for (int j = 0; j < 4; ++j)
                    acc[i][j] = __builtin_amdgcn_mfma_f32_16x16x32_f16(af[i], bf[j], acc[i][j], 0, 0, 0);
        }
    }

    const int which = n0 >> 10;           // 0=Q 1=K 2=V
    const int ncol0 = n0 & 1023;
    const float* bias = (which == 0) ? bq : (which == 1) ? bk : bv;

    if (which < 2) {
        _Float16* O = which ? Kh : Qh;
#pragma unroll
        for (int i = 0; i < 4; ++i) {
            const long mb = m0 + wm + i * 16 + quad * 4;
#pragma unroll
            for (int j = 0; j < 4; ++j) {
                const int col = ncol0 + wn + j * 16 + l15;
                const float bb = bias[col];
                _Float16* op = O + mb * 1024 + col;
#pragma unroll
                for (int r = 0; r < 4; ++r)
                    op[(long)r * 1024] = (_Float16)(acc[i][j][r] + bb);
            }
        }
    } else {
#pragma unroll
        for (int i = 0; i < 4; ++i) {
            const long mb = m0 + wm + i * 16 + quad * 4;
            const int b = (int)(mb >> 11);
            const int s = (int)(mb & 2047);
#pragma unroll
            for (int j = 0; j < 4; ++j) {
                const int col = ncol0 + wn + j * 16 + l15;
                const float bb = bias[col];
                half4 h;
#pragma unroll
                for (int r = 0; r < 4; ++r) h[r] = (_Float16)(acc[i][j][r] + bb);
                *(half4*)(Vt + (long)b * 2097152 + (long)col * 2048 + s) = h;  // 4 consecutive seq
            }
        }
    }
}

// ---------------------------------------------------------------------------
// Generic bt-form GEMM: C[m][n] = sum_k A[m][k]*B[n][k], fp16 in, fp32 out
//   BK=64; grid (ntile, mtile, z);  z adds per-operand strides (batching)
// ---------------------------------------------------------------------------
__global__ __launch_bounds__(256, 2)
void gemm_bt(const _Float16* __restrict__ A, long sAz, int lda,
             const _Float16* __restrict__ B, long sBz, int ldb,
             float* __restrict__ C, long sCz, int ldc, int K)
{
    __shared__ __align__(16) _Float16 sA[128 * 64];
    __shared__ __align__(16) _Float16 sB[128 * 64];
    const int tid = threadIdx.x;
    const int lane = tid & 63, wave = tid >> 6;
    const int quad = lane >> 4, l15 = lane & 15;
    const int wm = (wave & 1) * 64, wn = (wave >> 1) * 64;
    const long m0 = (long)blockIdx.y * 128;
    const long n0 = (long)blockIdx.x * 128;

    const _Float16* Ab = A + (long)blockIdx.z * sAz + m0 * lda;
    const _Float16* Bb = B + (long)blockIdx.z * sBz + n0 * ldb;
    float* Cb = C + (long)blockIdx.z * sCz;

    long offA[4], offB[4];
    int ldsOff[4];
#pragma unroll
    for (int u = 0; u < 4; ++u) {
        const int c = tid + u * 256;
        offA[u] = (long)(c >> 3) * lda + (c & 7) * 8;
        offB[u] = (long)(c >> 3) * ldb + (c & 7) * 8;
        ldsOff[u] = c * 16;
    }

    floatx4 acc[4][4] = {};

    for (int k0 = 0; k0 < K; k0 += 64) {
        __syncthreads();
#pragma unroll
        for (int u = 0; u < 4; ++u) {
            ASYNC16(Ab + offA[u] + k0, (char*)sA + ldsOff[u]);
            ASYNC16(Bb + offB[u] + k0, (char*)sB + ldsOff[u]);
        }
        __syncthreads();
#pragma unroll
        for (int s = 0; s < 2; ++s) {
            half8 af[4], bf[4];
#pragma unroll
            for (int i = 0; i < 4; ++i) {
                af[i] = *(const half8*)(sA + (wm + i * 16 + l15) * 64 + s * 32 + quad * 8);
                bf[i] = *(const half8*)(sB + (wn + i * 16 + l15) * 64 + s * 32 + quad * 8);
            }
#pragma unroll
            for (int i = 0; i < 4; ++i)
#pragma unroll
                for (int j = 0; j < 4; ++j)
                    acc[i][j] = __builtin_amdgcn_mfma_f32_16x16x32_f16(af[i], bf[j], acc[i][j], 0, 0, 0);
        }
    }

#pragma unroll
    for (int i = 0; i < 4; ++i) {
        const long mb = m0 + wm + i * 16 + quad * 4;
#pragma unroll
        for (int j = 0; j < 4; ++j) {
            const long n = n0 + wn + j * 16 + l15;
            float* cp = Cb + mb * ldc + n;
#pragma unroll
            for (int r = 0; r < 4; ++r)
                cp[(long)r * ldc] = acc[i][j][r];
        }
    }
}

// ---------------------------------------------------------------------------
// Row softmax over 2048 fp32 scores; writes fp16 weights IN PLACE at the row
// start (context GEMM then uses lda = 4096 halfs). One block per row.
// ---------------------------------------------------------------------------
__global__ __launch_bounds__(256)
void softmax_rows(float* __restrict__ scores)
{
    float* row = scores + ((size_t)blockIdx.y * 2048 + blockIdx.x) * 2048;
    const int tid = threadIdx.x;
    const int wave = tid >> 6;
    float4 v0 = ((const float4*)row)[tid];        // elems 4t..4t+3
    float4 v1 = ((const float4*)row)[tid + 256];  // elems 1024+4t..
    __shared__ float red[8];

    float m = fmaxf(fmaxf(fmaxf(v0.x, v0.y), fmaxf(v0.z, v0.w)),
                    fmaxf(fmaxf(v1.x, v1.y), fmaxf(v1.z, v1.w)));
#pragma unroll
    for (int off = 32; off > 0; off >>= 1) m = fmaxf(m, __shfl_xor(m, off));
    if ((tid & 63) == 0) red[wave] = m;
    __syncthreads();
    m = fmaxf(fmaxf(red[0], red[1]), fmaxf(red[2], red[3]));

    float e[8];
    e[0] = __expf(v0.x - m); e[1] = __expf(v0.y - m);
    e[2] = __expf(v0.z - m); e[3] = __expf(v0.w - m);
    e[4] = __expf(v1.x - m); e[5] = __expf(v1.y - m);
    e[6] = __expf(v1.z - m); e[7] = __expf(v1.w - m);
    float s = ((e[0] + e[1]) + (e[2] + e[3])) + ((e[4] + e[5]) + (e[6] + e[7]));
#pragma unroll
    for (int off = 32; off > 0; off >>= 1) s += __shfl_xor(s, off);
    if ((tid & 63) == 0) red[4 + wave] = s;
    __syncthreads();
    s = (red[4] + red[5]) + (red[6] + red[7]);
    const float inv = 1.0f / s;

    _Float16* wrow = (_Float16*)row;
    half4 h0, h1;
#pragma unroll
    for (int r = 0; r < 4; ++r) h0[r] = (_Float16)(e[r] * inv);
#pragma unroll
    for (int r = 0; r < 4; ++r) h1[r] = (_Float16)(e[4 + r] * inv);
    ((half4*)wrow)[tid] = h0;
    ((half4*)wrow)[tid + 256] = h1;
}

// ---------------------------------------------------------------------------
extern "C" void kernel_launch(void* const* d_in, const int* in_sizes, int n_in,
                              void* d_out, int out_size, void* d_ws, size_t ws_size,
                              hipStream_t stream)
{
    const float* x  = (const float*)d_in[0];
    const float* Wq = (const float*)d_in[1];
    const float* bq = (const float*)d_in[2];
    const float* Wk = (const float*)d_in[3];
    const float* bk = (const float*)d_in[4];
    const float* Wv = (const float*)d_in[5];
    const float* bv = (const float*)d_in[6];
    float* out = (float*)d_out;

    char* ws = (char*)d_ws;
    _Float16* Qh = (_Float16*)ws;          // [16384][1024] fp16
    _Float16* Kh = Qh + 16777216;          // [16384][1024] fp16
    _Float16* Vt = Kh + 16777216;          // 8 x [1024][2048] fp16 (V transposed per batch)
    char* region = ws + 100663296;         // shared region: (xh+Wt) then scores
    _Float16* xh = (_Float16*)region;      // [16384][1024] fp16   (dead after QKV GEMM)
    _Float16* Wt = xh + 16777216;          // [3072][1024] fp16    (dead after QKV GEMM)
    float* scores = (float*)region;        // c x [2048][2048] fp32 (overwrites xh/Wt)

    // pick batch-chunk c so that 100663296 + max(39845888, c*16MiB) fits ws
    int c = 8;
    for (;;) {
        size_t region_sz = (size_t)c * 16777216ull;       // c * 2048*2048*4 B
        if (region_sz < 39845888ull) region_sz = 39845888ull;
        if (100663296ull + region_sz <= ws_size || c == 1) break;
        c >>= 1;
    }

    cvt_f2h<<<2048, 256, 0, stream>>>(x, xh, 16777216 / 4);
    transpose_w<<<dim3(32, 32, 3), dim3(32, 8, 1), 0, stream>>>(Wq, Wk, Wv, Wt);
    gemm_qkv<<<dim3(24, 128, 1), 256, 0, stream>>>(xh, Wt, bq, bk, bv, Qh, Kh, Vt);

    for (int b0 = 0; b0 < 8; b0 += c) {
        int cc = (8 - b0 < c) ? (8 - b0) : c;
        // scores[z] = Q_b @ K_b^T   (M=N=2048, K=1024)
        gemm_bt<<<dim3(16, 16, cc), 256, 0, stream>>>(
            Qh + (long)b0 * 2097152, 2097152L, 1024,
            Kh + (long)b0 * 2097152, 2097152L, 1024,
            scores, 4194304L, 2048, 1024);
        // softmax per row, fp16 weights written in place (row stride 4096 halfs)
        softmax_rows<<<dim3(2048, cc, 1), 256, 0, stream>>>(scores);
        // context[z] = P @ V  via bt-form with Vt[n=d][k=seq]  (M=2048,N=1024,K=2048)
        gemm_bt<<<dim3(8, 16, cc), 256, 0, stream>>>(
            (const _Float16*)scores, 8388608L, 4096,
            Vt + (long)b0 * 2097152, 2097152L, 2048,
            out + (long)b0 * 2097152, 2097152L, 1024, 2048);
    }
}

// Round 3
// 423.541 us; speedup vs baseline: 1.1493x; 1.1171x over previous
//
#include <hip/hip_runtime.h>

typedef _Float16 half8 __attribute__((ext_vector_type(8)));
typedef _Float16 half4 __attribute__((ext_vector_type(4)));
typedef float floatx4 __attribute__((ext_vector_type(4)));

#define ASYNC16(g, l) __builtin_amdgcn_global_load_lds( \
    (const __attribute__((address_space(1))) void*)(g),  \
    (__attribute__((address_space(3))) void*)(l), 16, 0, 0)

// ---------------------------------------------------------------------------
// fp32 -> fp16 bulk convert (vectorized, grid-stride)
// ---------------------------------------------------------------------------
__global__ void cvt_f2h(const float* __restrict__ in, _Float16* __restrict__ out, int n4)
{
    int i = blockIdx.x * blockDim.x + threadIdx.x;
    const int stride = gridDim.x * blockDim.x;
    for (; i < n4; i += stride) {
        float4 v = ((const float4*)in)[i];
        half4 h = { (_Float16)v.x, (_Float16)v.y, (_Float16)v.z, (_Float16)v.w };
        ((half4*)out)[i] = h;
    }
}

// ---------------------------------------------------------------------------
// W [K=1024][N=1024] fp32  ->  Wt [N][K] fp16   (z = which of Wq/Wk/Wv)
// ---------------------------------------------------------------------------
__global__ void transpose_w(const float* __restrict__ Wq, const float* __restrict__ Wk,
                            const float* __restrict__ Wv, _Float16* __restrict__ Wt)
{
    const float* W = (blockIdx.z == 0) ? Wq : (blockIdx.z == 1) ? Wk : Wv;
    _Float16* out = Wt + (size_t)blockIdx.z * 1024 * 1024;
    __shared__ float t[32][33];
    const int tx = threadIdx.x, ty = threadIdx.y;     // (32,8)
    const int k0 = blockIdx.x * 32, n0 = blockIdx.y * 32;
#pragma unroll
    for (int i = 0; i < 32; i += 8)
        t[ty + i][tx] = W[(size_t)(k0 + ty + i) * 1024 + n0 + tx];   // t[k][n]
    __syncthreads();
#pragma unroll
    for (int i = 0; i < 32; i += 8)
        out[(size_t)(n0 + ty + i) * 1024 + k0 + tx] = (_Float16)t[tx][ty + i];  // out[n][k]=W[k][n]
}

// ---------------------------------------------------------------------------
// QKV GEMM: C[16384 x 3072] = xh[16384x1024] @ [Wq|Wk|Wv] + bias
//   Wt is [3072][1024] (transposed), 128x128 tile, BK=64, 4 waves (2x2 of 64x64)
//   LDS XOR-swizzle: slot c holds global chunk (c&7)^((c>>3)&7) of row c>>3
//   (16B chunks). Readers XOR chunk index with row&7 -> 2-way banks (free).
//   epilogue: Q,K row-major fp16; V transposed per batch (Vt[b][d][s]) fp16
// ---------------------------------------------------------------------------
__global__ __launch_bounds__(256, 2)
void gemm_qkv(const _Float16* __restrict__ X, const _Float16* __restrict__ Wt,
              const float* __restrict__ bq, const float* __restrict__ bk,
              const float* __restrict__ bv,
              _Float16* __restrict__ Qh, _Float16* __restrict__ Kh, _Float16* __restrict__ Vt)
{
    __shared__ __align__(16) _Float16 sA[128 * 64];
    __shared__ __align__(16) _Float16 sB[128 * 64];
    const int tid = threadIdx.x;
    const int lane = tid & 63, wave = tid >> 6;
    const int quad = lane >> 4, l15 = lane & 15;
    const int wm = (wave & 1) * 64, wn = (wave >> 1) * 64;
    const long m0 = (long)blockIdx.y * 128;
    const int  n0 = blockIdx.x * 128;

    const _Float16* Ab = X + m0 * 1024;
    const _Float16* Bb = Wt + (long)n0 * 1024;

    // staging: slot c -> row c>>3, global chunk (c&7)^(row&7)
    long offA[4];
    int ldsOff[4];
#pragma unroll
    for (int u = 0; u < 4; ++u) {
        const int c = tid + u * 256;
        const int row = c >> 3, g = (c & 7) ^ (row & 7);
        offA[u] = (long)row * 1024 + g * 8;
        ldsOff[u] = c * 16;
    }
    const int sw = l15 & 7;   // row&7 for this lane's fragment rows

    floatx4 acc[4][4] = {};

    for (int k0 = 0; k0 < 1024; k0 += 64) {
        __syncthreads();
#pragma unroll
        for (int u = 0; u < 4; ++u) {
            ASYNC16(Ab + offA[u] + k0, (char*)sA + ldsOff[u]);
            ASYNC16(Bb + offA[u] + k0, (char*)sB + ldsOff[u]);
        }
        __syncthreads();
#pragma unroll
        for (int s = 0; s < 2; ++s) {
            const int ck = ((s * 4 + quad) ^ sw) * 8;   // swizzled chunk offset (halves)
            half8 af[4], bf[4];
#pragma unroll
            for (int i = 0; i < 4; ++i) {
                af[i] = *(const half8*)(sA + (wm + i * 16 + l15) * 64 + ck);
                bf[i] = *(const half8*)(sB + (wn + i * 16 + l15) * 64 + ck);
            }
#pragma unroll
            for (int i = 0; i < 4; ++i)
#pragma unroll
                for (int j = 0; j < 4; ++j)
                    acc[i][j] = __builtin_amdgcn_mfma_f32_16x16x32_f16(af[i], bf[j], acc[i][j], 0, 0, 0);
        }
    }

    const int which = n0 >> 10;           // 0=Q 1=K 2=V
    const int ncol0 = n0 & 1023;
    const float* bias = (which == 0) ? bq : (which == 1) ? bk : bv;

    if (which < 2) {
        _Float16* O = which ? Kh : Qh;
#pragma unroll
        for (int i = 0; i < 4; ++i) {
            const long mb = m0 + wm + i * 16 + quad * 4;
#pragma unroll
            for (int j = 0; j < 4; ++j) {
                const int col = ncol0 + wn + j * 16 + l15;
                const float bb = bias[col];
                _Float16* op = O + mb * 1024 + col;
#pragma unroll
                for (int r = 0; r < 4; ++r)
                    op[(long)r * 1024] = (_Float16)(acc[i][j][r] + bb);
            }
        }
    } else {
#pragma unroll
        for (int i = 0; i < 4; ++i) {
            const long mb = m0 + wm + i * 16 + quad * 4;
            const int b = (int)(mb >> 11);
            const int s = (int)(mb & 2047);
#pragma unroll
            for (int j = 0; j < 4; ++j) {
                const int col = ncol0 + wn + j * 16 + l15;
                const float bb = bias[col];
                half4 h;
#pragma unroll
                for (int r = 0; r < 4; ++r) h[r] = (_Float16)(acc[i][j][r] + bb);
                *(half4*)(Vt + (long)b * 2097152 + (long)col * 2048 + s) = h;  // 4 consecutive seq
            }
        }
    }
}

// ---------------------------------------------------------------------------
// Generic bt-form GEMM: C[m][n] = sum_k A[m][k]*B[n][k], fp16 in, fp32 out
//   BK=64, XOR-swizzled LDS; grid (ntile, mtile, z); z adds per-operand strides
// ---------------------------------------------------------------------------
__global__ __launch_bounds__(256, 2)
void gemm_bt(const _Float16* __restrict__ A, long sAz, int lda,
             const _Float16* __restrict__ B, long sBz, int ldb,
             float* __restrict__ C, long sCz, int ldc, int K)
{
    __shared__ __align__(16) _Float16 sA[128 * 64];
    __shared__ __align__(16) _Float16 sB[128 * 64];
    const int tid = threadIdx.x;
    const int lane = tid & 63, wave = tid >> 6;
    const int quad = lane >> 4, l15 = lane & 15;
    const int wm = (wave & 1) * 64, wn = (wave >> 1) * 64;
    const long m0 = (long)blockIdx.y * 128;
    const long n0 = (long)blockIdx.x * 128;

    const _Float16* Ab = A + (long)blockIdx.z * sAz + m0 * lda;
    const _Float16* Bb = B + (long)blockIdx.z * sBz + n0 * ldb;
    float* Cb = C + (long)blockIdx.z * sCz;

    long offA[4], offB[4];
    int ldsOff[4];
#pragma unroll
    for (int u = 0; u < 4; ++u) {
        const int c = tid + u * 256;
        const int row = c >> 3, g = (c & 7) ^ (row & 7);
        offA[u] = (long)row * lda + g * 8;
        offB[u] = (long)row * ldb + g * 8;
        ldsOff[u] = c * 16;
    }
    const int sw = l15 & 7;

    floatx4 acc[4][4] = {};

    for (int k0 = 0; k0 < K; k0 += 64) {
        __syncthreads();
#pragma unroll
        for (int u = 0; u < 4; ++u) {
            ASYNC16(Ab + offA[u] + k0, (char*)sA + ldsOff[u]);
            ASYNC16(Bb + offB[u] + k0, (char*)sB + ldsOff[u]);
        }
        __syncthreads();
#pragma unroll
        for (int s = 0; s < 2; ++s) {
            const int ck = ((s * 4 + quad) ^ sw) * 8;
            half8 af[4], bf[4];
#pragma unroll
            for (int i = 0; i < 4; ++i) {
                af[i] = *(const half8*)(sA + (wm + i * 16 + l15) * 64 + ck);
                bf[i] = *(const half8*)(sB + (wn + i * 16 + l15) * 64 + ck);
            }
#pragma unroll
            for (int i = 0; i < 4; ++i)
#pragma unroll
                for (int j = 0; j < 4; ++j)
                    acc[i][j] = __builtin_amdgcn_mfma_f32_16x16x32_f16(af[i], bf[j], acc[i][j], 0, 0, 0);
        }
    }

#pragma unroll
    for (int i = 0; i < 4; ++i) {
        const long mb = m0 + wm + i * 16 + quad * 4;
#pragma unroll
        for (int j = 0; j < 4; ++j) {
            const long n = n0 + wn + j * 16 + l15;
            float* cp = Cb + mb * ldc + n;
#pragma unroll
            for (int r = 0; r < 4; ++r)
                cp[(long)r * ldc] = acc[i][j][r];
        }
    }
}

// ---------------------------------------------------------------------------
// Row softmax over 2048 fp32 scores; writes fp16 weights IN PLACE at the row
// start (context GEMM then uses lda = 4096 halfs). One block per row.
// ---------------------------------------------------------------------------
__global__ __launch_bounds__(256)
void softmax_rows(float* __restrict__ scores)
{
    float* row = scores + ((size_t)blockIdx.y * 2048 + blockIdx.x) * 2048;
    const int tid = threadIdx.x;
    const int wave = tid >> 6;
    float4 v0 = ((const float4*)row)[tid];        // elems 4t..4t+3
    float4 v1 = ((const float4*)row)[tid + 256];  // elems 1024+4t..
    __shared__ float red[8];

    float m = fmaxf(fmaxf(fmaxf(v0.x, v0.y), fmaxf(v0.z, v0.w)),
                    fmaxf(fmaxf(v1.x, v1.y), fmaxf(v1.z, v1.w)));
#pragma unroll
    for (int off = 32; off > 0; off >>= 1) m = fmaxf(m, __shfl_xor(m, off));
    if ((tid & 63) == 0) red[wave] = m;
    __syncthreads();
    m = fmaxf(fmaxf(red[0], red[1]), fmaxf(red[2], red[3]));

    float e[8];
    e[0] = __expf(v0.x - m); e[1] = __expf(v0.y - m);
    e[2] = __expf(v0.z - m); e[3] = __expf(v0.w - m);
    e[4] = __expf(v1.x - m); e[5] = __expf(v1.y - m);
    e[6] = __expf(v1.z - m); e[7] = __expf(v1.w - m);
    float s = ((e[0] + e[1]) + (e[2] + e[3])) + ((e[4] + e[5]) + (e[6] + e[7]));
#pragma unroll
    for (int off = 32; off > 0; off >>= 1) s += __shfl_xor(s, off);
    if ((tid & 63) == 0) red[4 + wave] = s;
    __syncthreads();
    s = (red[4] + red[5]) + (red[6] + red[7]);
    const float inv = 1.0f / s;

    _Float16* wrow = (_Float16*)row;
    half4 h0, h1;
#pragma unroll
    for (int r = 0; r < 4; ++r) h0[r] = (_Float16)(e[r] * inv);
#pragma unroll
    for (int r = 0; r < 4; ++r) h1[r] = (_Float16)(e[4 + r] * inv);
    ((half4*)wrow)[tid] = h0;
    ((half4*)wrow)[tid + 256] = h1;
}

// ---------------------------------------------------------------------------
extern "C" void kernel_launch(void* const* d_in, const int* in_sizes, int n_in,
                              void* d_out, int out_size, void* d_ws, size_t ws_size,
                              hipStream_t stream)
{
    const float* x  = (const float*)d_in[0];
    const float* Wq = (const float*)d_in[1];
    const float* bq = (const float*)d_in[2];
    const float* Wk = (const float*)d_in[3];
    const float* bk = (const float*)d_in[4];
    const float* Wv = (const float*)d_in[5];
    const float* bv = (const float*)d_in[6];
    float* out = (float*)d_out;

    char* ws = (char*)d_ws;
    _Float16* Qh = (_Float16*)ws;          // [16384][1024] fp16
    _Float16* Kh = Qh + 16777216;          // [16384][1024] fp16
    _Float16* Vt = Kh + 16777216;          // 8 x [1024][2048] fp16 (V transposed per batch)
    char* region = ws + 100663296;         // shared region: (xh+Wt) then scores
    _Float16* xh = (_Float16*)region;      // [16384][1024] fp16   (dead after QKV GEMM)
    _Float16* Wt = xh + 16777216;          // [3072][1024] fp16    (dead after QKV GEMM)
    float* scores = (float*)region;        // c x [2048][2048] fp32 (overwrites xh/Wt)

    // pick batch-chunk c so that 100663296 + max(39845888, c*16MiB) fits ws
    int c = 8;
    for (;;) {
        size_t region_sz = (size_t)c * 16777216ull;       // c * 2048*2048*4 B
        if (region_sz < 39845888ull) region_sz = 39845888ull;
        if (100663296ull + region_sz <= ws_size || c == 1) break;
        c >>= 1;
    }

    cvt_f2h<<<2048, 256, 0, stream>>>(x, xh, 16777216 / 4);
    transpose_w<<<dim3(32, 32, 3), dim3(32, 8, 1), 0, stream>>>(Wq, Wk, Wv, Wt);
    gemm_qkv<<<dim3(24, 128, 1), 256, 0, stream>>>(xh, Wt, bq, bk, bv, Qh, Kh, Vt);

    for (int b0 = 0; b0 < 8; b0 += c) {
        int cc = (8 - b0 < c) ? (8 - b0) : c;
        // scores[z] = Q_b @ K_b^T   (M=N=2048, K=1024)
        gemm_bt<<<dim3(16, 16, cc), 256, 0, stream>>>(
            Qh + (long)b0 * 2097152, 2097152L, 1024,
            Kh + (long)b0 * 2097152, 2097152L, 1024,
            scores, 4194304L, 2048, 1024);
        // softmax per row, fp16 weights written in place (row stride 4096 halfs)
        softmax_rows<<<dim3(2048, cc, 1), 256, 0, stream>>>(scores);
        // context[z] = P @ V  via bt-form with Vt[n=d][k=seq]  (M=2048,N=1024,K=2048)
        gemm_bt<<<dim3(8, 16, cc), 256, 0, stream>>>(
            (const _Float16*)scores, 8388608L, 4096,
            Vt + (long)b0 * 2097152, 2097152L, 2048,
            out + (long)b0 * 2097152, 2097152L, 1024, 2048);
    }
}

// Round 4
// 412.754 us; speedup vs baseline: 1.1793x; 1.0261x over previous
//
#include <hip/hip_runtime.h>

typedef _Float16 half8 __attribute__((ext_vector_type(8)));
typedef _Float16 half4 __attribute__((ext_vector_type(4)));
typedef short short8 __attribute__((ext_vector_type(8)));
typedef unsigned short ushort4v __attribute__((ext_vector_type(4)));
typedef float floatx4 __attribute__((ext_vector_type(4)));

#define ASYNC16(g, l) __builtin_amdgcn_global_load_lds( \
    (const __attribute__((address_space(1))) void*)(g),  \
    (__attribute__((address_space(3))) void*)(l), 16, 0, 0)

__device__ inline unsigned short f2bf(float f) {          // RNE fp32->bf16
    unsigned u = __builtin_bit_cast(unsigned, f);
    u += 0x7fff + ((u >> 16) & 1);
    return (unsigned short)(u >> 16);
}
__device__ inline float bf2f(unsigned short b) {
    unsigned u = (unsigned)b << 16;
    return __builtin_bit_cast(float, u);
}

// ---------------------------------------------------------------------------
// fp32 -> fp16 bulk convert (vectorized, grid-stride)
// ---------------------------------------------------------------------------
__global__ void cvt_f2h(const float* __restrict__ in, _Float16* __restrict__ out, int n4)
{
    int i = blockIdx.x * blockDim.x + threadIdx.x;
    const int stride = gridDim.x * blockDim.x;
    for (; i < n4; i += stride) {
        float4 v = ((const float4*)in)[i];
        half4 h = { (_Float16)v.x, (_Float16)v.y, (_Float16)v.z, (_Float16)v.w };
        ((half4*)out)[i] = h;
    }
}

// ---------------------------------------------------------------------------
// W [K=1024][N=1024] fp32  ->  Wt [N][K] fp16   (z = which of Wq/Wk/Wv)
// ---------------------------------------------------------------------------
__global__ void transpose_w(const float* __restrict__ Wq, const float* __restrict__ Wk,
                            const float* __restrict__ Wv, _Float16* __restrict__ Wt)
{
    const float* W = (blockIdx.z == 0) ? Wq : (blockIdx.z == 1) ? Wk : Wv;
    _Float16* out = Wt + (size_t)blockIdx.z * 1024 * 1024;
    __shared__ float t[32][33];
    const int tx = threadIdx.x, ty = threadIdx.y;     // (32,8)
    const int k0 = blockIdx.x * 32, n0 = blockIdx.y * 32;
#pragma unroll
    for (int i = 0; i < 32; i += 8)
        t[ty + i][tx] = W[(size_t)(k0 + ty + i) * 1024 + n0 + tx];   // t[k][n]
    __syncthreads();
#pragma unroll
    for (int i = 0; i < 32; i += 8)
        out[(size_t)(n0 + ty + i) * 1024 + k0 + tx] = (_Float16)t[tx][ty + i];  // out[n][k]=W[k][n]
}

// ---------------------------------------------------------------------------
// QKV GEMM: C[16384 x 3072] = xh[16384x1024] @ [Wq|Wk|Wv] + bias
//   128x128 tile, BK=64, XOR-swizzled LDS (zero bank conflicts — R3)
//   epilogue: Q,K row-major fp16; V transposed per batch, BF16 (Vt[b][d][s])
// ---------------------------------------------------------------------------
__global__ __launch_bounds__(256, 2)
void gemm_qkv(const _Float16* __restrict__ X, const _Float16* __restrict__ Wt,
              const float* __restrict__ bq, const float* __restrict__ bk,
              const float* __restrict__ bv,
              _Float16* __restrict__ Qh, _Float16* __restrict__ Kh,
              unsigned short* __restrict__ Vt)
{
    __shared__ __align__(16) _Float16 sA[128 * 64];
    __shared__ __align__(16) _Float16 sB[128 * 64];
    const int tid = threadIdx.x;
    const int lane = tid & 63, wave = tid >> 6;
    const int quad = lane >> 4, l15 = lane & 15;
    const int wm = (wave & 1) * 64, wn = (wave >> 1) * 64;
    const long m0 = (long)blockIdx.y * 128;
    const int  n0 = blockIdx.x * 128;

    const _Float16* Ab = X + m0 * 1024;
    const _Float16* Bb = Wt + (long)n0 * 1024;

    long offA[4];
    int ldsOff[4];
#pragma unroll
    for (int u = 0; u < 4; ++u) {
        const int c = tid + u * 256;
        const int row = c >> 3, g = (c & 7) ^ (row & 7);
        offA[u] = (long)row * 1024 + g * 8;
        ldsOff[u] = c * 16;
    }
    const int sw = l15 & 7;

    floatx4 acc[4][4] = {};

    for (int k0 = 0; k0 < 1024; k0 += 64) {
        __syncthreads();
#pragma unroll
        for (int u = 0; u < 4; ++u) {
            ASYNC16(Ab + offA[u] + k0, (char*)sA + ldsOff[u]);
            ASYNC16(Bb + offA[u] + k0, (char*)sB + ldsOff[u]);
        }
        __syncthreads();
#pragma unroll
        for (int s = 0; s < 2; ++s) {
            const int ck = ((s * 4 + quad) ^ sw) * 8;
            half8 af[4], bf[4];
#pragma unroll
            for (int i = 0; i < 4; ++i) {
                af[i] = *(const half8*)(sA + (wm + i * 16 + l15) * 64 + ck);
                bf[i] = *(const half8*)(sB + (wn + i * 16 + l15) * 64 + ck);
            }
#pragma unroll
            for (int i = 0; i < 4; ++i)
#pragma unroll
                for (int j = 0; j < 4; ++j)
                    acc[i][j] = __builtin_amdgcn_mfma_f32_16x16x32_f16(af[i], bf[j], acc[i][j], 0, 0, 0);
        }
    }

    const int which = n0 >> 10;           // 0=Q 1=K 2=V
    const int ncol0 = n0 & 1023;
    const float* bias = (which == 0) ? bq : (which == 1) ? bk : bv;

    if (which < 2) {
        _Float16* O = which ? Kh : Qh;
#pragma unroll
        for (int i = 0; i < 4; ++i) {
            const long mb = m0 + wm + i * 16 + quad * 4;
#pragma unroll
            for (int j = 0; j < 4; ++j) {
                const int col = ncol0 + wn + j * 16 + l15;
                const float bb = bias[col];
                _Float16* op = O + mb * 1024 + col;
#pragma unroll
                for (int r = 0; r < 4; ++r)
                    op[(long)r * 1024] = (_Float16)(acc[i][j][r] + bb);
            }
        }
    } else {
#pragma unroll
        for (int i = 0; i < 4; ++i) {
            const long mb = m0 + wm + i * 16 + quad * 4;
            const int b = (int)(mb >> 11);
            const int s = (int)(mb & 2047);
#pragma unroll
            for (int j = 0; j < 4; ++j) {
                const int col = ncol0 + wn + j * 16 + l15;
                const float bb = bias[col];
                ushort4v h;
#pragma unroll
                for (int r = 0; r < 4; ++r) h[r] = f2bf(acc[i][j][r] + bb);
                *(ushort4v*)(Vt + (long)b * 2097152 + (long)col * 2048 + s) = h;
            }
        }
    }
}

// ---------------------------------------------------------------------------
// Scores GEMM + fused exp/rowsum: E[z][m][n] = exp(Q_m . K_n - 40)  (bf16)
//   rowsum[z][m] += partial sums (fp32 atomics; buffer pre-zeroed)
//   A=Q, B=K fp16, lda=ldb=1024, M=N=2048 per batch z
// ---------------------------------------------------------------------------
__global__ __launch_bounds__(256, 2)
void gemm_sc(const _Float16* __restrict__ Q, const _Float16* __restrict__ K,
             unsigned short* __restrict__ E, float* __restrict__ rowsum)
{
    __shared__ __align__(16) _Float16 sA[128 * 64];
    __shared__ __align__(16) _Float16 sB[128 * 64];
    const int tid = threadIdx.x;
    const int lane = tid & 63, wave = tid >> 6;
    const int quad = lane >> 4, l15 = lane & 15;
    const int wm = (wave & 1) * 64, wn = (wave >> 1) * 64;
    const long m0 = (long)blockIdx.y * 128;
    const long n0 = (long)blockIdx.x * 128;

    const _Float16* Ab = Q + (long)blockIdx.z * 2097152 + m0 * 1024;
    const _Float16* Bb = K + (long)blockIdx.z * 2097152 + n0 * 1024;
    unsigned short* Eb = E + (long)blockIdx.z * 4194304;
    float* rs = rowsum + (long)blockIdx.z * 2048;

    long offA[4];
    int ldsOff[4];
#pragma unroll
    for (int u = 0; u < 4; ++u) {
        const int c = tid + u * 256;
        const int row = c >> 3, g = (c & 7) ^ (row & 7);
        offA[u] = (long)row * 1024 + g * 8;
        ldsOff[u] = c * 16;
    }
    const int sw = l15 & 7;

    floatx4 acc[4][4] = {};

    for (int k0 = 0; k0 < 1024; k0 += 64) {
        __syncthreads();
#pragma unroll
        for (int u = 0; u < 4; ++u) {
            ASYNC16(Ab + offA[u] + k0, (char*)sA + ldsOff[u]);
            ASYNC16(Bb + offA[u] + k0, (char*)sB + ldsOff[u]);
        }
        __syncthreads();
#pragma unroll
        for (int s = 0; s < 2; ++s) {
            const int ck = ((s * 4 + quad) ^ sw) * 8;
            half8 af[4], bf[4];
#pragma unroll
            for (int i = 0; i < 4; ++i) {
                af[i] = *(const half8*)(sA + (wm + i * 16 + l15) * 64 + ck);
                bf[i] = *(const half8*)(sB + (wn + i * 16 + l15) * 64 + ck);
            }
#pragma unroll
            for (int i = 0; i < 4; ++i)
#pragma unroll
                for (int j = 0; j < 4; ++j)
                    acc[i][j] = __builtin_amdgcn_mfma_f32_16x16x32_f16(af[i], bf[j], acc[i][j], 0, 0, 0);
        }
    }

    // epilogue: E = exp(score - 40) in bf16, wave-reduced row partials -> atomics
#pragma unroll
    for (int i = 0; i < 4; ++i) {
        const int rowb = (int)(m0 + wm + i * 16 + quad * 4);
#pragma unroll
        for (int r = 0; r < 4; ++r) {
            float sl = 0.f;
#pragma unroll
            for (int j = 0; j < 4; ++j) {
                const long col = n0 + wn + j * 16 + l15;
                unsigned short b = f2bf(__expf(acc[i][j][r] - 40.0f));
                Eb[(long)(rowb + r) * 2048 + col] = b;
                sl += bf2f(b);            // sum the ROUNDED value (matches PV input)
            }
            sl += __shfl_xor(sl, 1);
            sl += __shfl_xor(sl, 2);
            sl += __shfl_xor(sl, 4);
            sl += __shfl_xor(sl, 8);      // sum over the 16-lane l15 group
            if (l15 == 0) atomicAdd(&rs[rowb + r], sl);
        }
    }
}

// ---------------------------------------------------------------------------
// Context GEMM (bf16): out[z][m][d] = (sum_k E[m][k] * Vt[d][k]) / rowsum[z][m]
//   A=E bf16 lda=2048, B=Vt bf16 ldb=2048, K=2048; C fp32 ldc=1024
// ---------------------------------------------------------------------------
__global__ __launch_bounds__(256, 2)
void gemm_pv(const unsigned short* __restrict__ E, const unsigned short* __restrict__ Vt,
             const float* __restrict__ rowsum, float* __restrict__ C)
{
    __shared__ __align__(16) unsigned short sA[128 * 64];
    __shared__ __align__(16) unsigned short sB[128 * 64];
    const int tid = threadIdx.x;
    const int lane = tid & 63, wave = tid >> 6;
    const int quad = lane >> 4, l15 = lane & 15;
    const int wm = (wave & 1) * 64, wn = (wave >> 1) * 64;
    const long m0 = (long)blockIdx.y * 128;
    const long n0 = (long)blockIdx.x * 128;

    const unsigned short* Ab = E + (long)blockIdx.z * 4194304 + m0 * 2048;
    const unsigned short* Bb = Vt + (long)blockIdx.z * 2097152 + n0 * 2048;
    const float* rs = rowsum + (long)blockIdx.z * 2048;
    float* Cb = C + (long)blockIdx.z * 2097152;

    long offA[4];
    int ldsOff[4];
#pragma unroll
    for (int u = 0; u < 4; ++u) {
        const int c = tid + u * 256;
        const int row = c >> 3, g = (c & 7) ^ (row & 7);
        offA[u] = (long)row * 2048 + g * 8;
        ldsOff[u] = c * 16;
    }
    const int sw = l15 & 7;

    floatx4 acc[4][4] = {};

    for (int k0 = 0; k0 < 2048; k0 += 64) {
        __syncthreads();
#pragma unroll
        for (int u = 0; u < 4; ++u) {
            ASYNC16(Ab + offA[u] + k0, (char*)sA + ldsOff[u]);
            ASYNC16(Bb + offA[u] + k0, (char*)sB + ldsOff[u]);
        }
        __syncthreads();
#pragma unroll
        for (int s = 0; s < 2; ++s) {
            const int ck = ((s * 4 + quad) ^ sw) * 8;
            short8 af[4], bf[4];
#pragma unroll
            for (int i = 0; i < 4; ++i) {
                af[i] = *(const short8*)(sA + (wm + i * 16 + l15) * 64 + ck);
                bf[i] = *(const short8*)(sB + (wn + i * 16 + l15) * 64 + ck);
            }
#pragma unroll
            for (int i = 0; i < 4; ++i)
#pragma unroll
                for (int j = 0; j < 4; ++j)
                    acc[i][j] = __builtin_amdgcn_mfma_f32_16x16x32_bf16(af[i], bf[j], acc[i][j], 0, 0, 0);
        }
    }

#pragma unroll
    for (int i = 0; i < 4; ++i) {
        const int rowb = (int)(m0 + wm + i * 16 + quad * 4);
#pragma unroll
        for (int r = 0; r < 4; ++r) {
            const float inv = 1.0f / rs[rowb + r];
            float* cp = Cb + (long)(rowb + r) * 1024 + n0 + wn + l15;
#pragma unroll
            for (int j = 0; j < 4; ++j)
                cp[j * 16] = acc[i][j][r] * inv;
        }
    }
}

// ---------------------------------------------------------------------------
extern "C" void kernel_launch(void* const* d_in, const int* in_sizes, int n_in,
                              void* d_out, int out_size, void* d_ws, size_t ws_size,
                              hipStream_t stream)
{
    const float* x  = (const float*)d_in[0];
    const float* Wq = (const float*)d_in[1];
    const float* bq = (const float*)d_in[2];
    const float* Wk = (const float*)d_in[3];
    const float* bk = (const float*)d_in[4];
    const float* Wv = (const float*)d_in[5];
    const float* bv = (const float*)d_in[6];
    float* out = (float*)d_out;

    char* ws = (char*)d_ws;
    _Float16* Qh = (_Float16*)ws;              // [16384][1024] fp16
    _Float16* Kh = Qh + 16777216;              // [16384][1024] fp16
    unsigned short* Vt = (unsigned short*)(Kh + 16777216);  // 8 x [1024][2048] bf16
    char* region = ws + 100663296;             // (xh+Wt) then E
    _Float16* xh = (_Float16*)region;          // [16384][1024] fp16 (dead after QKV)
    _Float16* Wt = xh + 16777216;              // [3072][1024] fp16  (dead after QKV)
    unsigned short* E = (unsigned short*)region;  // c x [2048][2048] bf16

    // chunk c: region = max(xh+Wt = 39845888, c*8388608); + rowsum 64KB
    int c = 8;
    size_t region_sz;
    for (;;) {
        region_sz = (size_t)c * 8388608ull;
        if (region_sz < 39845888ull) region_sz = 39845888ull;
        if (100663296ull + region_sz + 65536ull <= ws_size || c == 1) break;
        c >>= 1;
    }
    float* rowsum = (float*)(ws + 100663296 + region_sz);   // c x 2048 fp32

    cvt_f2h<<<2048, 256, 0, stream>>>(x, xh, 16777216 / 4);
    transpose_w<<<dim3(32, 32, 3), dim3(32, 8, 1), 0, stream>>>(Wq, Wk, Wv, Wt);
    gemm_qkv<<<dim3(24, 128, 1), 256, 0, stream>>>(xh, Wt, bq, bk, bv, Qh, Kh, Vt);

    for (int b0 = 0; b0 < 8; b0 += c) {
        int cc = (8 - b0 < c) ? (8 - b0) : c;
        hipMemsetAsync(rowsum, 0, (size_t)cc * 2048 * 4, stream);
        gemm_sc<<<dim3(16, 16, cc), 256, 0, stream>>>(
            Qh + (long)b0 * 2097152, Kh + (long)b0 * 2097152, E, rowsum);
        gemm_pv<<<dim3(8, 16, cc), 256, 0, stream>>>(
            E, Vt + (long)b0 * 2097152, rowsum, out + (long)b0 * 2097152);
    }
}